// Round 4
// baseline (3760.928 us; speedup 1.0000x reference)
//
#include <hip/hip_runtime.h>

#define BB 4
#define NN 16384
#define CC 64
#define NPOINT 1024
#define NSAMPLE 32

#define FPS_T 1024
#define PPT   16   // NN / FPS_T

#define REPEAT16(M) M(0) M(1) M(2) M(3) M(4) M(5) M(6) M(7) \
                    M(8) M(9) M(10) M(11) M(12) M(13) M(14) M(15)

// ---------------------------------------------------------------------------
// K1: FPS. One block/batch, 1024 threads, 16 pts each (strided p=j*1024+tid).
// x,y coords live in LDS (128 KB dynamic) -> re-read each iter at LDS BW.
// z coords live in 16 scalar VGPRs, pinned loop-carried by an empty asm so
// the compiler cannot sink the loads back into the loop (the R2/R3 failure).
// d (loop-carried) in VGPRs. Winner z is carried through the argmax reduce;
// winner x,y come from LDS -> no global loads in the iteration loop.
// Bit-exact vs reference: contract(off), separate mul/add, first-index argmax.
// ---------------------------------------------------------------------------
__global__ __launch_bounds__(FPS_T, 4) void fps_kernel(const float* __restrict__ xyz,
                                                       float* __restrict__ new_xyz) {
    #pragma clang fp contract(off)
    extern __shared__ float smem[];
    float* sx = smem;        // [NN]
    float* sy = smem + NN;   // [NN]

    const int b    = blockIdx.x;
    const int tid  = threadIdx.x;
    const int lane = tid & 63;
    const int wv   = tid >> 6;   // 0..15
    const float* bx = xyz + (size_t)b * NN * 3;

#define DECL(j) float z##j, d##j;
    REPEAT16(DECL)
#undef DECL

#define INIT(j) { const int p = (j) * FPS_T + tid;      \
                  sx[p] = bx[p * 3 + 0];                 \
                  sy[p] = bx[p * 3 + 1];                 \
                  z##j  = bx[p * 3 + 2];                 \
                  d##j  = 1e10f; }
    REPEAT16(INIT)
#undef INIT

    __shared__ __align__(16) float4 s_w[2][16];   // {val, idx-bits, z, pad} per wave

    __syncthreads();

    float cx = sx[0], cy = sy[0], cz = bx[2];   // farthest starts at index 0
    float* outb = new_xyz + (size_t)b * NPOINT * 3;

    for (int it = 0; it < NPOINT; ++it) {
        // Pin the z registers: "+v" makes them loop-carried, so the compiler
        // cannot rematerialize them as global reloads inside the loop.
        asm volatile("" : "+v"(z0), "+v"(z1), "+v"(z2),  "+v"(z3),
                          "+v"(z4), "+v"(z5), "+v"(z6),  "+v"(z7),
                          "+v"(z8), "+v"(z9), "+v"(z10), "+v"(z11),
                          "+v"(z12), "+v"(z13), "+v"(z14), "+v"(z15));

        if (tid == 0) {
            outb[it * 3 + 0] = cx;
            outb[it * 3 + 1] = cy;
            outb[it * 3 + 2] = cz;
        }

        // distance update + local argmax (ascending j => first global index wins)
        float best = -1.0f;
        float bz   = 0.0f;
        int   bj   = 0;
#define STEP(j) { const float lx = sx[(j) * FPS_T + tid];         \
                  const float ly = sy[(j) * FPS_T + tid];         \
                  const float dx = lx - cx;                        \
                  const float dy = ly - cy;                        \
                  const float dz = z##j - cz;                      \
                  const float t  = dx * dx + dy * dy + dz * dz;    \
                  const float nd = fminf(d##j, t);                 \
                  d##j = nd;                                       \
                  const bool gt = nd > best;                       \
                  bj   = gt ? (j)  : bj;                           \
                  bz   = gt ? z##j : bz;                           \
                  best = gt ? nd   : best; }
        REPEAT16(STEP)
#undef STEP
        int bidx = bj * FPS_T + tid;            // global index

        // 64-lane butterfly argmax; tie -> smaller global index; carry z
        #pragma unroll
        for (int m = 32; m >= 1; m >>= 1) {
            const float ov = __shfl_xor(best, m, 64);
            const int   oi = __shfl_xor(bidx, m, 64);
            const float oz = __shfl_xor(bz,   m, 64);
            if (ov > best || (ov == best && oi < bidx)) {
                best = ov; bidx = oi; bz = oz;
            }
        }
        if (lane == 0) {
            s_w[it & 1][wv] = make_float4(best, __int_as_float(bidx), bz, 0.0f);
        }
        __syncthreads();

        // every thread reduces the 16 wave winners (broadcast LDS reads)
        float4 w0 = s_w[it & 1][0];
        float bv = w0.x;
        int   bi = __float_as_int(w0.y);
        float bzz = w0.z;
        #pragma unroll
        for (int w = 1; w < 16; ++w) {
            const float4 ww = s_w[it & 1][w];
            const int    oi = __float_as_int(ww.y);
            if (ww.x > bv || (ww.x == bv && oi < bi)) {
                bv = ww.x; bi = oi; bzz = ww.z;
            }
        }

        // winner coords: x,y broadcast from LDS, z carried through the reduce
        cx = sx[bi];
        cy = sy[bi];
        cz = bzz;
    }
}

// ---------------------------------------------------------------------------
// K2: Ball query. One wave per query; ordered first-32 selection via ballot,
// early exit once 32 found. Exact arithmetic (contract off, rad2 = (float)0.04).
// ---------------------------------------------------------------------------
__global__ __launch_bounds__(256) void ballq_kernel(const float* __restrict__ xyz,
                                                    const float* __restrict__ new_xyz,
                                                    int* __restrict__ gidx) {
    #pragma clang fp contract(off)
    const int lane = threadIdx.x & 63;
    const int q    = blockIdx.x * 4 + (threadIdx.x >> 6);
    const int b    = q >> 10;                  // NPOINT = 1024
    const float* bx = xyz + (size_t)b * NN * 3;
    const float* nx = new_xyz + (size_t)q * 3;
    const float cx = nx[0], cy = nx[1], cz = nx[2];
    const float rad2 = 0.04f;  // f32 cast of python double 0.2**2 — NOT 0.2f*0.2f

    int* out  = gidx + (size_t)q * NSAMPLE;
    int taken = 0;
    int first = NN - 1;  // used only if zero neighbors (centroid is its own neighbor)

    for (int chunk = 0; chunk < NN / 64 && taken < NSAMPLE; ++chunk) {
        const int   i  = chunk * 64 + lane;
        const float dx = cx - bx[i * 3 + 0];
        const float dy = cy - bx[i * 3 + 1];
        const float dz = cz - bx[i * 3 + 2];
        const float t  = dx * dx + dy * dy + dz * dz;
        const bool ok  = !(t > rad2);          // keep iff NOT (d > r^2)
        const unsigned long long m = __ballot(ok);
        const int cnt = __popcll(m);
        if (taken == 0 && cnt > 0) first = chunk * 64 + (__ffsll((long long)m) - 1);
        if (ok) {
            const int rank = taken + __popcll(m & ((1ull << lane) - 1ull));
            if (rank < NSAMPLE) out[rank] = i;
        }
        taken += cnt;
    }
    const int sat = taken < NSAMPLE ? taken : NSAMPLE;
    if (lane >= sat && lane < NSAMPLE) out[lane] = (taken > 0) ? first : (NN - 1);
}

// ---------------------------------------------------------------------------
// K3: gather feats -> LDS, MLP1 (67->64) + relu, MLP2 (64->128) + relu,
// max over the 32 samples. One 256-thread block per query. FMA allowed
// (reference einsum goes through a GEMM — accumulation order is free).
// ---------------------------------------------------------------------------
__global__ __launch_bounds__(256) void mlp_kernel(const float* __restrict__ xyz,
                                                  const float* __restrict__ points,
                                                  const float* __restrict__ w1,
                                                  const float* __restrict__ b1,
                                                  const float* __restrict__ w2,
                                                  const float* __restrict__ b2,
                                                  const float* __restrict__ new_xyz,
                                                  const int*   __restrict__ gidx,
                                                  float* __restrict__ new_points) {
    __shared__ __align__(16) float feats[32][68];  // [0..2]=xyz-norm, [3]=pad, [4..67]=points
    __shared__ __align__(16) float h1s[32][64];
    __shared__ float pmax[2][128];

    const int q = blockIdx.x;
    const int b = q >> 10;
    const int t = threadIdx.x;

    // ---- phase A: gather features into LDS (8 threads per sample row) ----
    {
        const int k  = t >> 3;
        const int l8 = t & 7;
        const int gi = gidx[q * 32 + k];
        const float* prow = points + ((size_t)b * NN + gi) * CC;
        const float4 v0 = *(const float4*)(prow + l8 * 8);
        const float4 v1 = *(const float4*)(prow + l8 * 8 + 4);
        *(float4*)&feats[k][4 + l8 * 8] = v0;
        *(float4*)&feats[k][8 + l8 * 8] = v1;
        if (l8 == 0) {
            const float* pr = xyz + ((size_t)b * NN + gi) * 3;
            const float* nr = new_xyz + (size_t)q * 3;
            feats[k][0] = pr[0] - nr[0];
            feats[k][1] = pr[1] - nr[1];
            feats[k][2] = pr[2] - nr[2];
        }
    }

    // w1 row in registers (c1 = t & 63), loaded while feats land in LDS
    const int c1 = t & 63;
    float w1r[67];
    #pragma unroll
    for (int j = 0; j < 67; ++j) w1r[j] = w1[c1 * 67 + j];
    const float bb1 = b1[c1];
    __syncthreads();

    // ---- phase B: layer 1. Wave-uniform k => LDS broadcast reads ----
    const int kg = t >> 6;   // wave id, 0..3
    #pragma unroll
    for (int kk = 0; kk < 8; ++kk) {
        const int kr = kg * 8 + kk;
        float acc = bb1;
        acc += feats[kr][0] * w1r[0] + feats[kr][1] * w1r[1] + feats[kr][2] * w1r[2];
        #pragma unroll
        for (int j = 0; j < 64; j += 4) {
            const float4 f = *(const float4*)&feats[kr][4 + j];
            acc += f.x * w1r[3 + j] + f.y * w1r[4 + j] + f.z * w1r[5 + j] + f.w * w1r[6 + j];
        }
        h1s[kr][c1] = fmaxf(acc, 0.0f);
    }

    // w2 row in registers (o2 = t & 127); k split in halves across thread groups
    const int o2 = t & 127;
    const int kh = t >> 7;   // 0 or 1
    float w2r[64];
    #pragma unroll
    for (int j = 0; j < 64; ++j) w2r[j] = w2[o2 * 64 + j];
    const float bb2 = b2[o2];
    __syncthreads();

    // ---- phase C: layer 2 + running max over k ----
    float mx = -INFINITY;
    #pragma unroll
    for (int kk = 0; kk < 16; ++kk) {
        const int kr = kh * 16 + kk;
        float acc = bb2;
        #pragma unroll
        for (int j = 0; j < 64; j += 4) {
            const float4 h = *(const float4*)&h1s[kr][j];
            acc += h.x * w2r[j] + h.y * w2r[j + 1] + h.z * w2r[j + 2] + h.w * w2r[j + 3];
        }
        mx = fmaxf(mx, fmaxf(acc, 0.0f));
    }
    pmax[kh][o2] = mx;
    __syncthreads();
    if (t < 128) {
        new_points[(size_t)q * 128 + t] = fmaxf(pmax[0][t], pmax[1][t]);
    }
}

// ---------------------------------------------------------------------------
extern "C" void kernel_launch(void* const* d_in, const int* in_sizes, int n_in,
                              void* d_out, int out_size, void* d_ws, size_t ws_size,
                              hipStream_t stream) {
    const float* xyz    = (const float*)d_in[0];   // (4, 16384, 3)
    const float* points = (const float*)d_in[1];   // (4, 16384, 64)
    const float* w1     = (const float*)d_in[2];   // (64, 67)
    const float* b1     = (const float*)d_in[3];   // (64,)
    const float* w2     = (const float*)d_in[4];   // (128, 64)
    const float* b2     = (const float*)d_in[5];   // (128,)
    // d_in[6] = npoint (1024), fixed by the problem setup

    float* out_newxyz    = (float*)d_out;                       // 4*1024*3
    float* out_newpoints = (float*)d_out + (size_t)BB * NPOINT * 3;
    int*   gidx          = (int*)d_ws;                          // 4*1024*32 ints

    const size_t fps_lds = (size_t)2 * NN * sizeof(float);      // 128 KB dynamic
    // Host-side attribute set (not a stream op — graph-capture-safe, idempotent).
    (void)hipFuncSetAttribute((const void*)fps_kernel,
                              hipFuncAttributeMaxDynamicSharedMemorySize,
                              (int)fps_lds);

    fps_kernel<<<BB, FPS_T, fps_lds, stream>>>(xyz, out_newxyz);
    ballq_kernel<<<(BB * NPOINT) / 4, 256, 0, stream>>>(xyz, out_newxyz, gidx);
    mlp_kernel<<<BB * NPOINT, 256, 0, stream>>>(xyz, points, w1, b1, w2, b2,
                                                out_newxyz, gidx, out_newpoints);
}

// Round 5
// 2371.595 us; speedup vs baseline: 1.5858x; 1.5858x over previous
//
#include <hip/hip_runtime.h>

#define BB 4
#define NN 16384
#define CC 64
#define NPOINT 1024
#define NSAMPLE 32

#define FPS_T 1024
#define NCHUNK 256          // 64 points per chunk
#define NCELL 4096          // 16^3 Morton cells

// ---------------------------------------------------------------------------
// K1: Pruned FPS.
// Phase 0: Morton counting-sort of the batch's points into d_ws (float4:
//          x,y,z,origidx-bits), per-chunk AABBs from actual members.
// Main loop: per-iteration, chunk is active iff mindist2(AABB, c) could beat
// the chunk's cached max d (exact-conservative margin). Only active chunks
// re-read their 64 points (L2-hot float4) and update sd[] in LDS. Argmax =
// max over 256 cached per-chunk (d, ~origidx) packed keys.
// Bit-exact: contract(off) on distance math, min() no-op skipping only,
// first-original-index tie-break via packed key.
// ---------------------------------------------------------------------------
__global__ __launch_bounds__(FPS_T) void fps_kernel(const float* __restrict__ xyz,
                                                    float* __restrict__ new_xyz,
                                                    float4* __restrict__ sorted) {
    #pragma clang fp contract(off)
    extern __shared__ char smem_raw[];
    unsigned long long* ubkey = (unsigned long long*)smem_raw;          // 256
    unsigned long long* candk = ubkey + NCHUNK;                          // 4
    float*          sd    = (float*)(candk + 4);                         // 16384
    int*            hist  = (int*)(sd + NN);                             // 4096
    unsigned short* scode = (unsigned short*)(hist + NCELL);             // 16384
    float* lox = (float*)(scode + NN);                                   // 256 x6
    float* loy = lox + NCHUNK;
    float* loz = loy + NCHUNK;
    float* hix = loz + NCHUNK;
    float* hiy = hix + NCHUNK;
    float* hiz = hiy + NCHUNK;
    int* ubpos = (int*)(hiz + NCHUNK);                                   // 256
    int* list  = ubpos + NCHUNK;                                         // 256
    int* wsum  = list + NCHUNK;                                          // 16
    int* candp = wsum + 16;                                              // 4
    int* cnt   = candp + 4;                                              // 2

    const int b    = blockIdx.x;
    const int tid  = threadIdx.x;
    const int lane = tid & 63;
    const int wv   = tid >> 6;                  // 0..15
    const float* bx = xyz + (size_t)b * NN * 3;
    float4* sb = sorted + (size_t)b * NN;

    // ---------- phase 0a: histogram of Morton cell codes ----------
    #pragma unroll
    for (int j = 0; j < 4; ++j) hist[j * FPS_T + tid] = 0;
    __syncthreads();

    #pragma unroll
    for (int j = 0; j < 16; ++j) {
        const int p = j * FPS_T + tid;
        const float x = bx[p * 3 + 0], y = bx[p * 3 + 1], z = bx[p * 3 + 2];
        int cx = (int)(x * 16.0f); cx = cx > 15 ? 15 : (cx < 0 ? 0 : cx);
        int cy = (int)(y * 16.0f); cy = cy > 15 ? 15 : (cy < 0 ? 0 : cy);
        int cz = (int)(z * 16.0f); cz = cz > 15 ? 15 : (cz < 0 ? 0 : cz);
        int code = 0;
        #pragma unroll
        for (int i = 0; i < 4; ++i)
            code |= (((cx >> i) & 1) << (3 * i)) |
                    (((cy >> i) & 1) << (3 * i + 1)) |
                    (((cz >> i) & 1) << (3 * i + 2));
        scode[p] = (unsigned short)code;
        atomicAdd(&hist[code], 1);
    }
    __syncthreads();

    // ---------- phase 0b: exclusive scan of hist (4 cells / thread) ----------
    {
        const int h0 = hist[4 * tid + 0], h1 = hist[4 * tid + 1];
        const int h2 = hist[4 * tid + 2], h3 = hist[4 * tid + 3];
        const int s  = h0 + h1 + h2 + h3;
        int v = s;
        #pragma unroll
        for (int o = 1; o < 64; o <<= 1) {
            const int u = __shfl_up(v, o, 64);
            if (lane >= o) v += u;
        }
        if (lane == 63) wsum[wv] = v;
        __syncthreads();
        int base = 0;
        for (int w = 0; w < wv; ++w) base += wsum[w];
        const int e0 = base + v - s;
        hist[4 * tid + 0] = e0;
        hist[4 * tid + 1] = e0 + h0;
        hist[4 * tid + 2] = e0 + h0 + h1;
        hist[4 * tid + 3] = e0 + h0 + h1 + h2;
    }
    __syncthreads();

    // ---------- phase 0c: scatter sorted points to global ----------
    #pragma unroll
    for (int j = 0; j < 16; ++j) {
        const int p = j * FPS_T + tid;
        const float x = bx[p * 3 + 0], y = bx[p * 3 + 1], z = bx[p * 3 + 2];
        const int slot = atomicAdd(&hist[scode[p]], 1);
        sb[slot] = make_float4(x, y, z, __int_as_float(p));
    }
    // init sd
    #pragma unroll
    for (int j = 0; j < 16; ++j) sd[j * FPS_T + tid] = 1e10f;
    __syncthreads();   // drains the global scatter writes too

    // ---------- phase 0d: per-chunk AABB from actual members ----------
    for (int g = wv; g < NCHUNK; g += 16) {
        const float4 pt = sb[g * 64 + lane];
        float mnx = pt.x, mxx = pt.x, mny = pt.y, mxy = pt.y, mnz = pt.z, mxz = pt.z;
        #pragma unroll
        for (int m = 32; m >= 1; m >>= 1) {
            mnx = fminf(mnx, __shfl_xor(mnx, m, 64));
            mxx = fmaxf(mxx, __shfl_xor(mxx, m, 64));
            mny = fminf(mny, __shfl_xor(mny, m, 64));
            mxy = fmaxf(mxy, __shfl_xor(mxy, m, 64));
            mnz = fminf(mnz, __shfl_xor(mnz, m, 64));
            mxz = fmaxf(mxz, __shfl_xor(mxz, m, 64));
        }
        if (lane == 0) {
            lox[g] = mnx; hix[g] = mxx;
            loy[g] = mny; hiy[g] = mxy;
            loz[g] = mnz; hiz[g] = mxz;
        }
    }
    if (tid < NCHUNK) {
        ubkey[tid] = ((unsigned long long)__float_as_uint(1e10f)) << 32;
        ubpos[tid] = 0;
    }
    if (tid == 0) { cnt[0] = 0; cnt[1] = 0; }
    __syncthreads();

    // ---------- main loop ----------
    float ccx = bx[0], ccy = bx[1], ccz = bx[2];   // farthest starts at index 0
    float* outb = new_xyz + (size_t)b * NPOINT * 3;

    for (int it = 0; it < NPOINT; ++it) {
        if (tid == 0) {
            outb[it * 3 + 0] = ccx;
            outb[it * 3 + 1] = ccy;
            outb[it * 3 + 2] = ccz;
        }

        // --- 1. active-chunk test + compaction (first 4 waves) ---
        if (tid < NCHUNK) {
            float dx = fmaxf(fmaxf(lox[tid] - ccx, ccx - hix[tid]), 0.0f);
            float dy = fmaxf(fmaxf(loy[tid] - ccy, ccy - hiy[tid]), 0.0f);
            float dz = fmaxf(fmaxf(loz[tid] - ccz, ccz - hiz[tid]), 0.0f);
            const float mind2 = dx * dx + dy * dy + dz * dz;
            const float ubval = __uint_as_float((unsigned)(ubkey[tid] >> 32));
            if (!(mind2 > ubval * 1.001f)) {        // conservative skip margin
                const int pos = atomicAdd(&cnt[it & 1], 1);
                list[pos] = tid;
            }
        }
        if (tid == 1023) cnt[(it + 1) & 1] = 0;     // reset other buffer
        __syncthreads();

        // --- 2. update active chunks (round-robin over waves) ---
        const int A = cnt[it & 1];
        for (int a = wv; a < A; a += 16) {
            const int g = list[a];
            const int p = g * 64 + lane;
            const float4 pt = sb[p];
            const float dx = pt.x - ccx;
            const float dy = pt.y - ccy;
            const float dz = pt.z - ccz;
            const float t  = (dx * dx + dy * dy) + dz * dz;   // ref order, no FMA
            const float nd = fminf(sd[p], t);
            sd[p] = nd;
            unsigned long long key =
                (((unsigned long long)__float_as_uint(nd)) << 32) |
                (unsigned long long)(0xFFFFFFFFu - (unsigned)__float_as_int(pt.w));
            int pos = p;
            #pragma unroll
            for (int m = 32; m >= 1; m >>= 1) {
                const unsigned long long ok = __shfl_xor(key, m, 64);
                const int op = __shfl_xor(pos, m, 64);
                if (ok > key) { key = ok; pos = op; }
            }
            if (lane == 0) { ubkey[g] = key; ubpos[g] = pos; }
        }
        __syncthreads();

        // --- 3. global argmax over 256 chunk keys ---
        if (tid < NCHUNK) {
            unsigned long long key = ubkey[tid];
            int pos = ubpos[tid];
            #pragma unroll
            for (int m = 32; m >= 1; m >>= 1) {
                const unsigned long long ok = __shfl_xor(key, m, 64);
                const int op = __shfl_xor(pos, m, 64);
                if (ok > key) { key = ok; pos = op; }
            }
            if (lane == 0) { candk[wv] = key; candp[wv] = pos; }
        }
        __syncthreads();

        unsigned long long bk = candk[0];
        int bp = candp[0];
        #pragma unroll
        for (int w = 1; w < 4; ++w) {
            if (candk[w] > bk) { bk = candk[w]; bp = candp[w]; }
        }
        const float4 win = sb[bp];     // broadcast, L2-hot
        ccx = win.x; ccy = win.y; ccz = win.z;
    }
}

// ---------------------------------------------------------------------------
// K2: Ball query. One wave per query; ordered first-32 selection via ballot,
// early exit once 32 found. Exact arithmetic (contract off, rad2 = (float)0.04).
// ---------------------------------------------------------------------------
__global__ __launch_bounds__(256) void ballq_kernel(const float* __restrict__ xyz,
                                                    const float* __restrict__ new_xyz,
                                                    int* __restrict__ gidx) {
    #pragma clang fp contract(off)
    const int lane = threadIdx.x & 63;
    const int q    = blockIdx.x * 4 + (threadIdx.x >> 6);
    const int b    = q >> 10;                  // NPOINT = 1024
    const float* bx = xyz + (size_t)b * NN * 3;
    const float* nx = new_xyz + (size_t)q * 3;
    const float cx = nx[0], cy = nx[1], cz = nx[2];
    const float rad2 = 0.04f;  // f32 cast of python double 0.2**2 — NOT 0.2f*0.2f

    int* out  = gidx + (size_t)q * NSAMPLE;
    int taken = 0;
    int first = NN - 1;

    for (int chunk = 0; chunk < NN / 64 && taken < NSAMPLE; ++chunk) {
        const int   i  = chunk * 64 + lane;
        const float dx = cx - bx[i * 3 + 0];
        const float dy = cy - bx[i * 3 + 1];
        const float dz = cz - bx[i * 3 + 2];
        const float t  = dx * dx + dy * dy + dz * dz;
        const bool ok  = !(t > rad2);
        const unsigned long long m = __ballot(ok);
        const int cnt = __popcll(m);
        if (taken == 0 && cnt > 0) first = chunk * 64 + (__ffsll((long long)m) - 1);
        if (ok) {
            const int rank = taken + __popcll(m & ((1ull << lane) - 1ull));
            if (rank < NSAMPLE) out[rank] = i;
        }
        taken += cnt;
    }
    const int sat = taken < NSAMPLE ? taken : NSAMPLE;
    if (lane >= sat && lane < NSAMPLE) out[lane] = (taken > 0) ? first : (NN - 1);
}

// ---------------------------------------------------------------------------
// K3: gather feats -> LDS, MLP1 (67->64) + relu, MLP2 (64->128) + relu,
// max over the 32 samples. One 256-thread block per query. FMA allowed.
// ---------------------------------------------------------------------------
__global__ __launch_bounds__(256) void mlp_kernel(const float* __restrict__ xyz,
                                                  const float* __restrict__ points,
                                                  const float* __restrict__ w1,
                                                  const float* __restrict__ b1,
                                                  const float* __restrict__ w2,
                                                  const float* __restrict__ b2,
                                                  const float* __restrict__ new_xyz,
                                                  const int*   __restrict__ gidx,
                                                  float* __restrict__ new_points) {
    __shared__ __align__(16) float feats[32][68];
    __shared__ __align__(16) float h1s[32][64];
    __shared__ float pmax[2][128];

    const int q = blockIdx.x;
    const int b = q >> 10;
    const int t = threadIdx.x;

    {
        const int k  = t >> 3;
        const int l8 = t & 7;
        const int gi = gidx[q * 32 + k];
        const float* prow = points + ((size_t)b * NN + gi) * CC;
        const float4 v0 = *(const float4*)(prow + l8 * 8);
        const float4 v1 = *(const float4*)(prow + l8 * 8 + 4);
        *(float4*)&feats[k][4 + l8 * 8] = v0;
        *(float4*)&feats[k][8 + l8 * 8] = v1;
        if (l8 == 0) {
            const float* pr = xyz + ((size_t)b * NN + gi) * 3;
            const float* nr = new_xyz + (size_t)q * 3;
            feats[k][0] = pr[0] - nr[0];
            feats[k][1] = pr[1] - nr[1];
            feats[k][2] = pr[2] - nr[2];
        }
    }

    const int c1 = t & 63;
    float w1r[67];
    #pragma unroll
    for (int j = 0; j < 67; ++j) w1r[j] = w1[c1 * 67 + j];
    const float bb1 = b1[c1];
    __syncthreads();

    const int kg = t >> 6;
    #pragma unroll
    for (int kk = 0; kk < 8; ++kk) {
        const int kr = kg * 8 + kk;
        float acc = bb1;
        acc += feats[kr][0] * w1r[0] + feats[kr][1] * w1r[1] + feats[kr][2] * w1r[2];
        #pragma unroll
        for (int j = 0; j < 64; j += 4) {
            const float4 f = *(const float4*)&feats[kr][4 + j];
            acc += f.x * w1r[3 + j] + f.y * w1r[4 + j] + f.z * w1r[5 + j] + f.w * w1r[6 + j];
        }
        h1s[kr][c1] = fmaxf(acc, 0.0f);
    }

    const int o2 = t & 127;
    const int kh = t >> 7;
    float w2r[64];
    #pragma unroll
    for (int j = 0; j < 64; ++j) w2r[j] = w2[o2 * 64 + j];
    const float bb2 = b2[o2];
    __syncthreads();

    float mx = -INFINITY;
    #pragma unroll
    for (int kk = 0; kk < 16; ++kk) {
        const int kr = kh * 16 + kk;
        float acc = bb2;
        #pragma unroll
        for (int j = 0; j < 64; j += 4) {
            const float4 h = *(const float4*)&h1s[kr][j];
            acc += h.x * w2r[j] + h.y * w2r[j + 1] + h.z * w2r[j + 2] + h.w * w2r[j + 3];
        }
        mx = fmaxf(mx, fmaxf(acc, 0.0f));
    }
    pmax[kh][o2] = mx;
    __syncthreads();
    if (t < 128) {
        new_points[(size_t)q * 128 + t] = fmaxf(pmax[0][t], pmax[1][t]);
    }
}

// ---------------------------------------------------------------------------
extern "C" void kernel_launch(void* const* d_in, const int* in_sizes, int n_in,
                              void* d_out, int out_size, void* d_ws, size_t ws_size,
                              hipStream_t stream) {
    const float* xyz    = (const float*)d_in[0];
    const float* points = (const float*)d_in[1];
    const float* w1     = (const float*)d_in[2];
    const float* b1     = (const float*)d_in[3];
    const float* w2     = (const float*)d_in[4];
    const float* b2     = (const float*)d_in[5];

    float* out_newxyz    = (float*)d_out;
    float* out_newpoints = (float*)d_out + (size_t)BB * NPOINT * 3;
    int*    gidx    = (int*)d_ws;                                   // 512 KB
    float4* sortbuf = (float4*)((char*)d_ws + (size_t)512 * 1024);  // 1 MB

    // dynamic LDS: ubkey 2048 + candk 32 + sd 65536 + hist 16384 + scode 32768
    //            + aabb 6144 + ubpos/list 2048 + wsum/candp/cnt 88 ~= 125 KB
    const int fps_lds = 125056;
    (void)hipFuncSetAttribute((const void*)fps_kernel,
                              hipFuncAttributeMaxDynamicSharedMemorySize,
                              fps_lds);

    fps_kernel<<<BB, FPS_T, fps_lds, stream>>>(xyz, out_newxyz, sortbuf);
    ballq_kernel<<<(BB * NPOINT) / 4, 256, 0, stream>>>(xyz, out_newxyz, gidx);
    mlp_kernel<<<BB * NPOINT, 256, 0, stream>>>(xyz, points, w1, b1, w2, b2,
                                                out_newxyz, gidx, out_newpoints);
}

// Round 6
// 2241.389 us; speedup vs baseline: 1.6779x; 1.0581x over previous
//
#include <hip/hip_runtime.h>

#define BB 4
#define NN 16384
#define CC 64
#define NPOINT 1024
#define NSAMPLE 32

#define FPS_T 1024
#define NCHUNK 256          // 64 points per chunk
#define NCELL 4096          // 16^3 Morton cells

// padded index for per-chunk arrays: lane k touches g = wv + 16k;
// g + (g>>4) makes banks distinct across k (conflict-free).
#define PAD(g) ((g) + ((g) >> 4))

// ---------------------------------------------------------------------------
// K1: Pruned FPS, single-barrier iteration.
// Phase 0: Morton counting-sort into d_ws (float4 x,y,z,origidx-bits),
//          per-chunk AABBs.
// Chunks are statically owned: wave wv owns chunks {wv, wv+16, ..., wv+240}
// (stride-16 interleave spreads spatially-clustered active chunks across
// waves). sd[] and ubkey[] are wave-private => no cross-wave hazards.
// Per iteration: test 16 owned AABBs (lane k), update active chunks
// (min() no-op skipping, exact-conservative margin), per-chunk key reduce,
// own-max over 16 cached keys, ONE ds-atomicMax on a double-buffered u64
// slot, ONE __syncthreads, broadcast winner (sorted slot packed in key).
// key = d_bits(32) | (0x3FFF-orig)(14+4) | sortedslot(14)  -> first-original-
// index tie-break is exact; slot recovery is free.
// ---------------------------------------------------------------------------
__global__ __launch_bounds__(FPS_T) void fps_kernel(const float* __restrict__ xyz,
                                                    float* __restrict__ new_xyz,
                                                    float4* __restrict__ sorted) {
    #pragma clang fp contract(off)
    extern __shared__ char smem_raw[];
    unsigned long long* slotk = (unsigned long long*)smem_raw;           // 2
    unsigned long long* ubkey = slotk + 2;                               // 272
    float* sd   = (float*)(ubkey + 272);                                 // 16384
    int*   hist = (int*)(sd + NN);                                       // 4096
    float* lox  = (float*)(hist + NCELL);                                // 272 x6
    float* loy  = lox + 272;
    float* loz  = loy + 272;
    float* hix  = loz + 272;
    float* hiy  = hix + 272;
    float* hiz  = hiy + 272;
    int*   wsum = (int*)(hiz + 272);                                     // 16

    const int b    = blockIdx.x;
    const int tid  = threadIdx.x;
    const int lane = tid & 63;
    const int wv   = tid >> 6;                  // 0..15
    const float* bx = xyz + (size_t)b * NN * 3;
    float4* sb = sorted + (size_t)b * NN;

    // ---------- phase 0a: histogram of Morton cell codes ----------
    #pragma unroll
    for (int j = 0; j < 4; ++j) hist[j * FPS_T + tid] = 0;
    __syncthreads();

    #pragma unroll
    for (int j = 0; j < 16; ++j) {
        const int p = j * FPS_T + tid;
        const float x = bx[p * 3 + 0], y = bx[p * 3 + 1], z = bx[p * 3 + 2];
        int cx = (int)(x * 16.0f); cx = cx > 15 ? 15 : (cx < 0 ? 0 : cx);
        int cy = (int)(y * 16.0f); cy = cy > 15 ? 15 : (cy < 0 ? 0 : cy);
        int cz = (int)(z * 16.0f); cz = cz > 15 ? 15 : (cz < 0 ? 0 : cz);
        int code = 0;
        #pragma unroll
        for (int i = 0; i < 4; ++i)
            code |= (((cx >> i) & 1) << (3 * i)) |
                    (((cy >> i) & 1) << (3 * i + 1)) |
                    (((cz >> i) & 1) << (3 * i + 2));
        atomicAdd(&hist[code], 1);
    }
    __syncthreads();

    // ---------- phase 0b: exclusive scan of hist (4 cells / thread) ----------
    {
        const int h0 = hist[4 * tid + 0], h1 = hist[4 * tid + 1];
        const int h2 = hist[4 * tid + 2], h3 = hist[4 * tid + 3];
        const int s  = h0 + h1 + h2 + h3;
        int v = s;
        #pragma unroll
        for (int o = 1; o < 64; o <<= 1) {
            const int u = __shfl_up(v, o, 64);
            if (lane >= o) v += u;
        }
        if (lane == 63) wsum[wv] = v;
        __syncthreads();
        int base = 0;
        for (int w = 0; w < wv; ++w) base += wsum[w];
        const int e0 = base + v - s;
        hist[4 * tid + 0] = e0;
        hist[4 * tid + 1] = e0 + h0;
        hist[4 * tid + 2] = e0 + h0 + h1;
        hist[4 * tid + 3] = e0 + h0 + h1 + h2;
    }
    __syncthreads();

    // ---------- phase 0c: scatter sorted points (recompute code) ----------
    #pragma unroll
    for (int j = 0; j < 16; ++j) {
        const int p = j * FPS_T + tid;
        const float x = bx[p * 3 + 0], y = bx[p * 3 + 1], z = bx[p * 3 + 2];
        int cx = (int)(x * 16.0f); cx = cx > 15 ? 15 : (cx < 0 ? 0 : cx);
        int cy = (int)(y * 16.0f); cy = cy > 15 ? 15 : (cy < 0 ? 0 : cy);
        int cz = (int)(z * 16.0f); cz = cz > 15 ? 15 : (cz < 0 ? 0 : cz);
        int code = 0;
        #pragma unroll
        for (int i = 0; i < 4; ++i)
            code |= (((cx >> i) & 1) << (3 * i)) |
                    (((cy >> i) & 1) << (3 * i + 1)) |
                    (((cz >> i) & 1) << (3 * i + 2));
        const int slot = atomicAdd(&hist[code], 1);
        sb[slot] = make_float4(x, y, z, __int_as_float(p));
    }
    // init sd
    #pragma unroll
    for (int j = 0; j < 16; ++j) sd[j * FPS_T + tid] = 1e10f;
    __syncthreads();   // drains scatter stores (vmcnt) before AABB readback

    // ---------- phase 0d: per-chunk AABB from actual members ----------
    for (int g = wv; g < NCHUNK; g += 16) {
        const float4 pt = sb[g * 64 + lane];
        float mnx = pt.x, mxx = pt.x, mny = pt.y, mxy = pt.y, mnz = pt.z, mxz = pt.z;
        #pragma unroll
        for (int m = 32; m >= 1; m >>= 1) {
            mnx = fminf(mnx, __shfl_xor(mnx, m, 64));
            mxx = fmaxf(mxx, __shfl_xor(mxx, m, 64));
            mny = fminf(mny, __shfl_xor(mny, m, 64));
            mxy = fmaxf(mxy, __shfl_xor(mxy, m, 64));
            mnz = fminf(mnz, __shfl_xor(mnz, m, 64));
            mxz = fmaxf(mxz, __shfl_xor(mxz, m, 64));
        }
        if (lane == 0) {
            lox[PAD(g)] = mnx; hix[PAD(g)] = mxx;
            loy[PAD(g)] = mny; hiy[PAD(g)] = mxy;
            loz[PAD(g)] = mnz; hiz[PAD(g)] = mxz;
        }
    }
    if (tid < NCHUNK) {
        ubkey[PAD(tid)] = ((unsigned long long)__float_as_uint(1e10f)) << 32;
    }
    if (tid == 0) { slotk[0] = 0ull; slotk[1] = 0ull; }
    __syncthreads();

    // ---------- main loop: ONE barrier per iteration ----------
    float ccx = bx[0], ccy = bx[1], ccz = bx[2];   // farthest starts at index 0
    float* outb = new_xyz + (size_t)b * NPOINT * 3;

    for (int it = 0; it < NPOINT; ++it) {
        if (tid == 0) {
            outb[it * 3 + 0] = ccx;
            outb[it * 3 + 1] = ccy;
            outb[it * 3 + 2] = ccz;
        }

        // --- test my 16 owned chunks (lane k -> chunk wv+16k) ---
        bool active = false;
        if (lane < 16) {
            const int g = wv + (lane << 4);
            const float dx = fmaxf(fmaxf(lox[PAD(g)] - ccx, ccx - hix[PAD(g)]), 0.0f);
            const float dy = fmaxf(fmaxf(loy[PAD(g)] - ccy, ccy - hiy[PAD(g)]), 0.0f);
            const float dz = fmaxf(fmaxf(loz[PAD(g)] - ccz, ccz - hiz[PAD(g)]), 0.0f);
            const float mind2 = dx * dx + dy * dy + dz * dz;
            const float ubval = __uint_as_float((unsigned)(ubkey[PAD(g)] >> 32));
            active = !(mind2 > ubval * 1.001f);    // conservative skip margin
        }
        unsigned mask = (unsigned)(__ballot(active) & 0xFFFFull);  // wave-uniform

        // --- update active owned chunks ---
        while (mask) {
            const int k = __ffs(mask) - 1;
            mask &= mask - 1;
            const int g = wv + (k << 4);
            const int p = (g << 6) + lane;
            const float4 pt = sb[p];
            const float dx = pt.x - ccx;
            const float dy = pt.y - ccy;
            const float dz = pt.z - ccz;
            const float t  = (dx * dx + dy * dy) + dz * dz;   // ref order, no FMA
            const float nd = fminf(sd[p], t);
            sd[p] = nd;
            const unsigned orig = (unsigned)__float_as_int(pt.w);
            unsigned long long key =
                (((unsigned long long)__float_as_uint(nd)) << 32) |
                ((unsigned long long)(0x3FFFu - orig) << 14) |
                (unsigned long long)(unsigned)p;
            #pragma unroll
            for (int m = 32; m >= 1; m >>= 1) {
                const unsigned long long ok = __shfl_xor(key, m, 64);
                key = ok > key ? ok : key;
            }
            if (lane == 0) ubkey[PAD(g)] = key;
        }

        // --- own-max over my 16 cached chunk keys -> one LDS atomic ---
        unsigned long long wmax = 0ull;
        if (lane < 16) wmax = ubkey[PAD(wv + (lane << 4))];
        #pragma unroll
        for (int m = 8; m >= 1; m >>= 1) {
            const unsigned long long ok = __shfl_xor(wmax, m, 64);
            wmax = ok > wmax ? ok : wmax;
        }
        if (lane == 0) atomicMax(&slotk[it & 1], wmax);
        if (tid == 0) slotk[(it + 1) & 1] = 0ull;   // reset other buffer
        __syncthreads();

        // --- winner: sorted slot is packed in the key; broadcast L2 load ---
        const unsigned long long wk = slotk[it & 1];
        const int srt = (int)(wk & 0x3FFFull);
        const float4 win = sb[srt];
        ccx = win.x; ccy = win.y; ccz = win.z;
    }
}

// ---------------------------------------------------------------------------
// K2: Ball query. One wave per query; ordered first-32 selection via ballot,
// early exit once 32 found. Exact arithmetic (contract off, rad2 = (float)0.04).
// ---------------------------------------------------------------------------
__global__ __launch_bounds__(256) void ballq_kernel(const float* __restrict__ xyz,
                                                    const float* __restrict__ new_xyz,
                                                    int* __restrict__ gidx) {
    #pragma clang fp contract(off)
    const int lane = threadIdx.x & 63;
    const int q    = blockIdx.x * 4 + (threadIdx.x >> 6);
    const int b    = q >> 10;                  // NPOINT = 1024
    const float* bx = xyz + (size_t)b * NN * 3;
    const float* nx = new_xyz + (size_t)q * 3;
    const float cx = nx[0], cy = nx[1], cz = nx[2];
    const float rad2 = 0.04f;  // f32 cast of python double 0.2**2 — NOT 0.2f*0.2f

    int* out  = gidx + (size_t)q * NSAMPLE;
    int taken = 0;
    int first = NN - 1;

    for (int chunk = 0; chunk < NN / 64 && taken < NSAMPLE; ++chunk) {
        const int   i  = chunk * 64 + lane;
        const float dx = cx - bx[i * 3 + 0];
        const float dy = cy - bx[i * 3 + 1];
        const float dz = cz - bx[i * 3 + 2];
        const float t  = dx * dx + dy * dy + dz * dz;
        const bool ok  = !(t > rad2);
        const unsigned long long m = __ballot(ok);
        const int cnt = __popcll(m);
        if (taken == 0 && cnt > 0) first = chunk * 64 + (__ffsll((long long)m) - 1);
        if (ok) {
            const int rank = taken + __popcll(m & ((1ull << lane) - 1ull));
            if (rank < NSAMPLE) out[rank] = i;
        }
        taken += cnt;
    }
    const int sat = taken < NSAMPLE ? taken : NSAMPLE;
    if (lane >= sat && lane < NSAMPLE) out[lane] = (taken > 0) ? first : (NN - 1);
}

// ---------------------------------------------------------------------------
// K3: gather feats -> LDS, MLP1 (67->64) + relu, MLP2 (64->128) + relu,
// max over the 32 samples. One 256-thread block per query. FMA allowed.
// ---------------------------------------------------------------------------
__global__ __launch_bounds__(256) void mlp_kernel(const float* __restrict__ xyz,
                                                  const float* __restrict__ points,
                                                  const float* __restrict__ w1,
                                                  const float* __restrict__ b1,
                                                  const float* __restrict__ w2,
                                                  const float* __restrict__ b2,
                                                  const float* __restrict__ new_xyz,
                                                  const int*   __restrict__ gidx,
                                                  float* __restrict__ new_points) {
    __shared__ __align__(16) float feats[32][68];
    __shared__ __align__(16) float h1s[32][64];
    __shared__ float pmax[2][128];

    const int q = blockIdx.x;
    const int b = q >> 10;
    const int t = threadIdx.x;

    {
        const int k  = t >> 3;
        const int l8 = t & 7;
        const int gi = gidx[q * 32 + k];
        const float* prow = points + ((size_t)b * NN + gi) * CC;
        const float4 v0 = *(const float4*)(prow + l8 * 8);
        const float4 v1 = *(const float4*)(prow + l8 * 8 + 4);
        *(float4*)&feats[k][4 + l8 * 8] = v0;
        *(float4*)&feats[k][8 + l8 * 8] = v1;
        if (l8 == 0) {
            const float* pr = xyz + ((size_t)b * NN + gi) * 3;
            const float* nr = new_xyz + (size_t)q * 3;
            feats[k][0] = pr[0] - nr[0];
            feats[k][1] = pr[1] - nr[1];
            feats[k][2] = pr[2] - nr[2];
        }
    }

    const int c1 = t & 63;
    float w1r[67];
    #pragma unroll
    for (int j = 0; j < 67; ++j) w1r[j] = w1[c1 * 67 + j];
    const float bb1 = b1[c1];
    __syncthreads();

    const int kg = t >> 6;
    #pragma unroll
    for (int kk = 0; kk < 8; ++kk) {
        const int kr = kg * 8 + kk;
        float acc = bb1;
        acc += feats[kr][0] * w1r[0] + feats[kr][1] * w1r[1] + feats[kr][2] * w1r[2];
        #pragma unroll
        for (int j = 0; j < 64; j += 4) {
            const float4 f = *(const float4*)&feats[kr][4 + j];
            acc += f.x * w1r[3 + j] + f.y * w1r[4 + j] + f.z * w1r[5 + j] + f.w * w1r[6 + j];
        }
        h1s[kr][c1] = fmaxf(acc, 0.0f);
    }

    const int o2 = t & 127;
    const int kh = t >> 7;
    float w2r[64];
    #pragma unroll
    for (int j = 0; j < 64; ++j) w2r[j] = w2[o2 * 64 + j];
    const float bb2 = b2[o2];
    __syncthreads();

    float mx = -INFINITY;
    #pragma unroll
    for (int kk = 0; kk < 16; ++kk) {
        const int kr = kh * 16 + kk;
        float acc = bb2;
        #pragma unroll
        for (int j = 0; j < 64; j += 4) {
            const float4 h = *(const float4*)&h1s[kr][j];
            acc += h.x * w2r[j] + h.y * w2r[j + 1] + h.z * w2r[j + 2] + h.w * w2r[j + 3];
        }
        mx = fmaxf(mx, fmaxf(acc, 0.0f));
    }
    pmax[kh][o2] = mx;
    __syncthreads();
    if (t < 128) {
        new_points[(size_t)q * 128 + t] = fmaxf(pmax[0][t], pmax[1][t]);
    }
}

// ---------------------------------------------------------------------------
extern "C" void kernel_launch(void* const* d_in, const int* in_sizes, int n_in,
                              void* d_out, int out_size, void* d_ws, size_t ws_size,
                              hipStream_t stream) {
    const float* xyz    = (const float*)d_in[0];
    const float* points = (const float*)d_in[1];
    const float* w1     = (const float*)d_in[2];
    const float* b1     = (const float*)d_in[3];
    const float* w2     = (const float*)d_in[4];
    const float* b2     = (const float*)d_in[5];

    float* out_newxyz    = (float*)d_out;
    float* out_newpoints = (float*)d_out + (size_t)BB * NPOINT * 3;
    int*    gidx    = (int*)d_ws;                                   // 512 KB
    float4* sortbuf = (float4*)((char*)d_ws + (size_t)512 * 1024);  // 1 MB

    // dynamic LDS: slotk 16 + ubkey 2176 + sd 65536 + hist 16384
    //            + aabb 6*1088 + wsum 64  ~= 90.8 KB
    const int fps_lds = 16 + 2176 + 65536 + 16384 + 6 * 1088 + 64;
    (void)hipFuncSetAttribute((const void*)fps_kernel,
                              hipFuncAttributeMaxDynamicSharedMemorySize,
                              fps_lds);

    fps_kernel<<<BB, FPS_T, fps_lds, stream>>>(xyz, out_newxyz, sortbuf);
    ballq_kernel<<<(BB * NPOINT) / 4, 256, 0, stream>>>(xyz, out_newxyz, gidx);
    mlp_kernel<<<BB * NPOINT, 256, 0, stream>>>(xyz, points, w1, b1, w2, b2,
                                                out_newxyz, gidx, out_newpoints);
}

// Round 7
// 2115.477 us; speedup vs baseline: 1.7778x; 1.0595x over previous
//
#include <hip/hip_runtime.h>

#define BB 4
#define NN 16384
#define CC 64
#define NPOINT 1024
#define NSAMPLE 32

#define FPS_T 1024
#define NCHUNK 256          // 64 points per chunk
#define NCELL 4096          // 16^3 Morton cells

// padded index for per-chunk LDS arrays (conflict-free across lane k strides)
#define PAD(g) ((g) + ((g) >> 4))

// ---------------------------------------------------------------------------
// K1: Pruned FPS, register-resident state, single barrier, zero global loads
// in the iteration chain.
// Phase 0: Morton counting-sort into d_ws (float4 x,y,z,origidx-bits),
//          per-chunk AABBs -> then preloaded into registers.
// Ownership: wave wv owns chunks {wv+16k}; lane k holds that chunk's AABB,
// ub, and full cached argmax key in REGISTERS; lane L holds d of point
// (g*64+L) for each owned chunk in dreg[16] (static-unrolled, SROA->VGPR).
// Per iteration: VALU AABB test -> ballot -> per-active-chunk: global L2
// point load, d update, f32 butterfly max + ballot winner (u32 tie fallback),
// winner lane writes chunk argmax coords to LDS ubc4[g]; lane k caches key.
// Own-max: 4-level u64 butterfly (lanes 0..15) -> one LDS atomicMax ->
// ONE barrier -> slot read -> ubc4 broadcast read = new centroid.
// key = d_bits(32) | (0x3FFF-orig)<<8 | g  -> exact first-orig-index
// tie-break; g recovery free.
// Bit-exact: contract(off), (dx*dx+dy*dy)+dz*dz order, min() no-op skips
// with conservative margin, ties resolved to smallest original index.
// ---------------------------------------------------------------------------
__global__ __launch_bounds__(FPS_T) void fps_kernel(const float* __restrict__ xyz,
                                                    float* __restrict__ new_xyz,
                                                    float4* __restrict__ sorted) {
    #pragma clang fp contract(off)
    extern __shared__ char smem_raw[];
    unsigned long long* slotk = (unsigned long long*)smem_raw;           // 2
    float4* ubc4 = (float4*)(slotk + 2);                                 // 272
    int*   hist  = (int*)(ubc4 + 272);                                   // 4096
    float* lox   = (float*)(hist + NCELL);                               // 272 x6
    float* loy   = lox + 272;
    float* loz   = loy + 272;
    float* hix   = loz + 272;
    float* hiy   = hix + 272;
    float* hiz   = hiy + 272;
    int*   wsum  = (int*)(hiz + 272);                                    // 16

    const int b    = blockIdx.x;
    const int tid  = threadIdx.x;
    const int lane = tid & 63;
    const int wv   = tid >> 6;                  // 0..15
    const float* bx = xyz + (size_t)b * NN * 3;
    float4* sb = sorted + (size_t)b * NN;

    // ---------- phase 0a: histogram of Morton cell codes ----------
    #pragma unroll
    for (int j = 0; j < 4; ++j) hist[j * FPS_T + tid] = 0;
    __syncthreads();

    #pragma unroll
    for (int j = 0; j < 16; ++j) {
        const int p = j * FPS_T + tid;
        const float x = bx[p * 3 + 0], y = bx[p * 3 + 1], z = bx[p * 3 + 2];
        int cx = (int)(x * 16.0f); cx = cx > 15 ? 15 : (cx < 0 ? 0 : cx);
        int cy = (int)(y * 16.0f); cy = cy > 15 ? 15 : (cy < 0 ? 0 : cy);
        int cz = (int)(z * 16.0f); cz = cz > 15 ? 15 : (cz < 0 ? 0 : cz);
        int code = 0;
        #pragma unroll
        for (int i = 0; i < 4; ++i)
            code |= (((cx >> i) & 1) << (3 * i)) |
                    (((cy >> i) & 1) << (3 * i + 1)) |
                    (((cz >> i) & 1) << (3 * i + 2));
        atomicAdd(&hist[code], 1);
    }
    __syncthreads();

    // ---------- phase 0b: exclusive scan of hist ----------
    {
        const int h0 = hist[4 * tid + 0], h1 = hist[4 * tid + 1];
        const int h2 = hist[4 * tid + 2], h3 = hist[4 * tid + 3];
        const int s  = h0 + h1 + h2 + h3;
        int v = s;
        #pragma unroll
        for (int o = 1; o < 64; o <<= 1) {
            const int u = __shfl_up(v, o, 64);
            if (lane >= o) v += u;
        }
        if (lane == 63) wsum[wv] = v;
        __syncthreads();
        int base = 0;
        for (int w = 0; w < wv; ++w) base += wsum[w];
        const int e0 = base + v - s;
        hist[4 * tid + 0] = e0;
        hist[4 * tid + 1] = e0 + h0;
        hist[4 * tid + 2] = e0 + h0 + h1;
        hist[4 * tid + 3] = e0 + h0 + h1 + h2;
    }
    __syncthreads();

    // ---------- phase 0c: scatter sorted points (recompute code) ----------
    #pragma unroll
    for (int j = 0; j < 16; ++j) {
        const int p = j * FPS_T + tid;
        const float x = bx[p * 3 + 0], y = bx[p * 3 + 1], z = bx[p * 3 + 2];
        int cx = (int)(x * 16.0f); cx = cx > 15 ? 15 : (cx < 0 ? 0 : cx);
        int cy = (int)(y * 16.0f); cy = cy > 15 ? 15 : (cy < 0 ? 0 : cy);
        int cz = (int)(z * 16.0f); cz = cz > 15 ? 15 : (cz < 0 ? 0 : cz);
        int code = 0;
        #pragma unroll
        for (int i = 0; i < 4; ++i)
            code |= (((cx >> i) & 1) << (3 * i)) |
                    (((cy >> i) & 1) << (3 * i + 1)) |
                    (((cz >> i) & 1) << (3 * i + 2));
        const int slot = atomicAdd(&hist[code], 1);
        sb[slot] = make_float4(x, y, z, __int_as_float(p));
    }
    __syncthreads();   // drains scatter stores before AABB readback

    // ---------- phase 0d: per-chunk AABB ----------
    for (int g = wv; g < NCHUNK; g += 16) {
        const float4 pt = sb[g * 64 + lane];
        float mnx = pt.x, mxx = pt.x, mny = pt.y, mxy = pt.y, mnz = pt.z, mxz = pt.z;
        #pragma unroll
        for (int m = 32; m >= 1; m >>= 1) {
            mnx = fminf(mnx, __shfl_xor(mnx, m, 64));
            mxx = fmaxf(mxx, __shfl_xor(mxx, m, 64));
            mny = fminf(mny, __shfl_xor(mny, m, 64));
            mxy = fmaxf(mxy, __shfl_xor(mxy, m, 64));
            mnz = fminf(mnz, __shfl_xor(mnz, m, 64));
            mxz = fmaxf(mxz, __shfl_xor(mxz, m, 64));
        }
        if (lane == 0) {
            lox[PAD(g)] = mnx; hix[PAD(g)] = mxx;
            loy[PAD(g)] = mny; hiy[PAD(g)] = mxy;
            loz[PAD(g)] = mnz; hiz[PAD(g)] = mxz;
        }
    }
    if (tid == 0) { slotk[0] = 0ull; slotk[1] = 0ull; }
    __syncthreads();

    // ---------- preload per-lane register state ----------
    float abx0 = 0.f, aby0 = 0.f, abz0 = 0.f, abx1 = 0.f, aby1 = 0.f, abz1 = 0.f;
    if (lane < 16) {
        const int g = wv + (lane << 4);
        abx0 = lox[PAD(g)]; abx1 = hix[PAD(g)];
        aby0 = loy[PAD(g)]; aby1 = hiy[PAD(g)];
        abz0 = loz[PAD(g)]; abz1 = hiz[PAD(g)];
    }
    float ubval = 1e10f;                 // lane k: ub of chunk wv+16k
    unsigned long long ubkeyreg = 0ull;  // lane k: cached argmax key of chunk
    float dreg[16];                      // lane L: d of point (wv+16k)*64+L
    #pragma unroll
    for (int k = 0; k < 16; ++k) dreg[k] = 1e10f;

    // ---------- main loop: ONE barrier per iteration ----------
    float ccx = bx[0], ccy = bx[1], ccz = bx[2];   // farthest starts at index 0
    float* outb = new_xyz + (size_t)b * NPOINT * 3;

    for (int it = 0; it < NPOINT; ++it) {
        if (tid == 0) {
            outb[it * 3 + 0] = ccx;
            outb[it * 3 + 1] = ccy;
            outb[it * 3 + 2] = ccz;
        }

        // --- AABB test, all in registers ---
        bool active = false;
        if (lane < 16) {
            const float dx = fmaxf(fmaxf(abx0 - ccx, ccx - abx1), 0.0f);
            const float dy = fmaxf(fmaxf(aby0 - ccy, ccy - aby1), 0.0f);
            const float dz = fmaxf(fmaxf(abz0 - ccz, ccz - abz1), 0.0f);
            const float mind2 = dx * dx + dy * dy + dz * dz;
            active = !(mind2 > ubval * 1.001f);    // conservative skip margin
        }
        const unsigned umask = (unsigned)(__ballot(active) & 0xFFFFull);

        // --- update active owned chunks (static unroll, uniform branches) ---
        #pragma unroll
        for (int k = 0; k < 16; ++k) {
            if (umask & (1u << k)) {
                const int g = wv + (k << 4);
                const int p = (g << 6) + lane;
                const float4 pt = sb[p];
                const float dx = pt.x - ccx;
                const float dy = pt.y - ccy;
                const float dz = pt.z - ccz;
                const float t  = (dx * dx + dy * dy) + dz * dz;   // ref order
                const float nd = fminf(dreg[k], t);
                dreg[k] = nd;
                // wave max of nd (f32 butterfly)
                float m = nd;
                #pragma unroll
                for (int s = 32; s >= 1; s >>= 1)
                    m = fmaxf(m, __shfl_xor(m, s, 64));
                const unsigned orig = (unsigned)__float_as_int(pt.w);
                unsigned long long tied = __ballot(nd == m);
                if (__popcll(tied) > 1) {          // rare: exact tie on d
                    unsigned v = (nd == m) ? (0x3FFFu - orig) : 0u;
                    #pragma unroll
                    for (int s = 32; s >= 1; s >>= 1) {
                        const unsigned o = __shfl_xor(v, s, 64);
                        v = o > v ? o : v;
                    }
                    tied = __ballot(nd == m && (0x3FFFu - orig) == v);
                }
                const int wl = __ffsll((long long)tied) - 1;    // winner lane
                if (lane == wl) ubc4[PAD(g)] = make_float4(pt.x, pt.y, pt.z, 0.f);
                const unsigned worig = (unsigned)__shfl((int)orig, wl, 64);
                const unsigned long long fullkey =
                    (((unsigned long long)__float_as_uint(m)) << 32) |
                    ((unsigned long long)(0x3FFFu - worig) << 8) |
                    (unsigned long long)(unsigned)g;
                if (lane == k) { ubkeyreg = fullkey; ubval = m; }
            }
        }

        // --- own-max over 16 cached keys (lanes 0..15) -> one LDS atomic ---
        unsigned long long wmax = ubkeyreg;
        #pragma unroll
        for (int s = 8; s >= 1; s >>= 1) {
            const unsigned long long o = __shfl_xor(wmax, s, 64);
            wmax = o > wmax ? o : wmax;
        }
        if (lane == 0) atomicMax(&slotk[it & 1], wmax);
        if (tid == 0) slotk[(it + 1) & 1] = 0ull;
        __syncthreads();

        // --- winner: chunk id in key low bits; coords from LDS broadcast ---
        const unsigned long long wk = slotk[it & 1];
        const int gw = (int)(wk & 0xFFull);
        const float4 win = ubc4[PAD(gw)];
        ccx = win.x; ccy = win.y; ccz = win.z;
    }
}

// ---------------------------------------------------------------------------
// K2: Ball query. One wave per query; ordered first-32 selection via ballot,
// early exit once 32 found. Exact arithmetic (contract off, rad2 = (float)0.04).
// ---------------------------------------------------------------------------
__global__ __launch_bounds__(256) void ballq_kernel(const float* __restrict__ xyz,
                                                    const float* __restrict__ new_xyz,
                                                    int* __restrict__ gidx) {
    #pragma clang fp contract(off)
    const int lane = threadIdx.x & 63;
    const int q    = blockIdx.x * 4 + (threadIdx.x >> 6);
    const int b    = q >> 10;                  // NPOINT = 1024
    const float* bx = xyz + (size_t)b * NN * 3;
    const float* nx = new_xyz + (size_t)q * 3;
    const float cx = nx[0], cy = nx[1], cz = nx[2];
    const float rad2 = 0.04f;  // f32 cast of python double 0.2**2 — NOT 0.2f*0.2f

    int* out  = gidx + (size_t)q * NSAMPLE;
    int taken = 0;
    int first = NN - 1;

    for (int chunk = 0; chunk < NN / 64 && taken < NSAMPLE; ++chunk) {
        const int   i  = chunk * 64 + lane;
        const float dx = cx - bx[i * 3 + 0];
        const float dy = cy - bx[i * 3 + 1];
        const float dz = cz - bx[i * 3 + 2];
        const float t  = dx * dx + dy * dy + dz * dz;
        const bool ok  = !(t > rad2);
        const unsigned long long m = __ballot(ok);
        const int cnt = __popcll(m);
        if (taken == 0 && cnt > 0) first = chunk * 64 + (__ffsll((long long)m) - 1);
        if (ok) {
            const int rank = taken + __popcll(m & ((1ull << lane) - 1ull));
            if (rank < NSAMPLE) out[rank] = i;
        }
        taken += cnt;
    }
    const int sat = taken < NSAMPLE ? taken : NSAMPLE;
    if (lane >= sat && lane < NSAMPLE) out[lane] = (taken > 0) ? first : (NN - 1);
}

// ---------------------------------------------------------------------------
// K3: gather feats -> LDS, MLP1 (67->64) + relu, MLP2 (64->128) + relu,
// max over the 32 samples. One 256-thread block per query. FMA allowed.
// ---------------------------------------------------------------------------
__global__ __launch_bounds__(256) void mlp_kernel(const float* __restrict__ xyz,
                                                  const float* __restrict__ points,
                                                  const float* __restrict__ w1,
                                                  const float* __restrict__ b1,
                                                  const float* __restrict__ w2,
                                                  const float* __restrict__ b2,
                                                  const float* __restrict__ new_xyz,
                                                  const int*   __restrict__ gidx,
                                                  float* __restrict__ new_points) {
    __shared__ __align__(16) float feats[32][68];
    __shared__ __align__(16) float h1s[32][64];
    __shared__ float pmax[2][128];

    const int q = blockIdx.x;
    const int b = q >> 10;
    const int t = threadIdx.x;

    {
        const int k  = t >> 3;
        const int l8 = t & 7;
        const int gi = gidx[q * 32 + k];
        const float* prow = points + ((size_t)b * NN + gi) * CC;
        const float4 v0 = *(const float4*)(prow + l8 * 8);
        const float4 v1 = *(const float4*)(prow + l8 * 8 + 4);
        *(float4*)&feats[k][4 + l8 * 8] = v0;
        *(float4*)&feats[k][8 + l8 * 8] = v1;
        if (l8 == 0) {
            const float* pr = xyz + ((size_t)b * NN + gi) * 3;
            const float* nr = new_xyz + (size_t)q * 3;
            feats[k][0] = pr[0] - nr[0];
            feats[k][1] = pr[1] - nr[1];
            feats[k][2] = pr[2] - nr[2];
        }
    }

    const int c1 = t & 63;
    float w1r[67];
    #pragma unroll
    for (int j = 0; j < 67; ++j) w1r[j] = w1[c1 * 67 + j];
    const float bb1 = b1[c1];
    __syncthreads();

    const int kg = t >> 6;
    #pragma unroll
    for (int kk = 0; kk < 8; ++kk) {
        const int kr = kg * 8 + kk;
        float acc = bb1;
        acc += feats[kr][0] * w1r[0] + feats[kr][1] * w1r[1] + feats[kr][2] * w1r[2];
        #pragma unroll
        for (int j = 0; j < 64; j += 4) {
            const float4 f = *(const float4*)&feats[kr][4 + j];
            acc += f.x * w1r[3 + j] + f.y * w1r[4 + j] + f.z * w1r[5 + j] + f.w * w1r[6 + j];
        }
        h1s[kr][c1] = fmaxf(acc, 0.0f);
    }

    const int o2 = t & 127;
    const int kh = t >> 7;
    float w2r[64];
    #pragma unroll
    for (int j = 0; j < 64; ++j) w2r[j] = w2[o2 * 64 + j];
    const float bb2 = b2[o2];
    __syncthreads();

    float mx = -INFINITY;
    #pragma unroll
    for (int kk = 0; kk < 16; ++kk) {
        const int kr = kh * 16 + kk;
        float acc = bb2;
        #pragma unroll
        for (int j = 0; j < 64; j += 4) {
            const float4 h = *(const float4*)&h1s[kr][j];
            acc += h.x * w2r[j] + h.y * w2r[j + 1] + h.z * w2r[j + 2] + h.w * w2r[j + 3];
        }
        mx = fmaxf(mx, fmaxf(acc, 0.0f));
    }
    pmax[kh][o2] = mx;
    __syncthreads();
    if (t < 128) {
        new_points[(size_t)q * 128 + t] = fmaxf(pmax[0][t], pmax[1][t]);
    }
}

// ---------------------------------------------------------------------------
extern "C" void kernel_launch(void* const* d_in, const int* in_sizes, int n_in,
                              void* d_out, int out_size, void* d_ws, size_t ws_size,
                              hipStream_t stream) {
    const float* xyz    = (const float*)d_in[0];
    const float* points = (const float*)d_in[1];
    const float* w1     = (const float*)d_in[2];
    const float* b1     = (const float*)d_in[3];
    const float* w2     = (const float*)d_in[4];
    const float* b2     = (const float*)d_in[5];

    float* out_newxyz    = (float*)d_out;
    float* out_newpoints = (float*)d_out + (size_t)BB * NPOINT * 3;
    int*    gidx    = (int*)d_ws;                                   // 512 KB
    float4* sortbuf = (float4*)((char*)d_ws + (size_t)512 * 1024);  // 1 MB

    // dynamic LDS: slotk 16 + ubc4 4352 + hist 16384 + aabb 6*1088 + wsum 64
    const int fps_lds = 16 + 4352 + 16384 + 6 * 1088 + 64;   // ~27.3 KB
    (void)hipFuncSetAttribute((const void*)fps_kernel,
                              hipFuncAttributeMaxDynamicSharedMemorySize,
                              fps_lds);

    fps_kernel<<<BB, FPS_T, fps_lds, stream>>>(xyz, out_newxyz, sortbuf);
    ballq_kernel<<<(BB * NPOINT) / 4, 256, 0, stream>>>(xyz, out_newxyz, gidx);
    mlp_kernel<<<BB * NPOINT, 256, 0, stream>>>(xyz, points, w1, b1, w2, b2,
                                                out_newxyz, gidx, out_newpoints);
}